// Round 4
// baseline (441.170 us; speedup 1.0000x reference)
//
#include <hip/hip_runtime.h>
#include <math.h>

#define MSZ 4096
#define ISZ 2048
#define NSPLIT 64
#define KC (ISZ / NSPLIT)   // 32 rows per split

typedef float fx4 __attribute__((ext_vector_type(4)));

// ---------------------------------------------------------------------------
// Kernel A: split-K partial matvec for the 3 live gates (inpgate, outgate, inp)
// grid = 3 gates x 4 coltiles x NSPLIT splits = 768 blocks = 3 blocks/CU.
//
// Concurrency fix: BW*latency says we need ~9 KB/CU of reads in flight to
// approach HBM peak. 12 waves/CU x 32 dwordx4 = 24 KB/CU if ALL 32 loads per
// thread are issued before the first use. So: batch-load all 32 weight
// vectors into registers (128 VGPR, fits the 3-blocks/CU budget of ~170),
// then do the FMAs. No launch_bounds min-wave cap so regalloc can hold the
// batch without spilling.
// ---------------------------------------------------------------------------
__global__ __launch_bounds__(256) void k_matvec(
    const float* __restrict__ x,
    const float* __restrict__ w_inpgate,
    const float* __restrict__ w_outgate,
    const float* __restrict__ w_inp,
    float* __restrict__ z_part)
{
    const int b       = blockIdx.x;
    const int gate    = b / (4 * NSPLIT);
    const int rem     = b % (4 * NSPLIT);
    const int coltile = rem / NSPLIT;
    const int split   = rem % NSPLIT;

    const float* W = (gate == 0) ? w_inpgate : (gate == 1) ? w_outgate : w_inp;

    const int c4 = coltile * 256 + threadIdx.x;   // float4 column index, 0..1023
    const fx4* Wp = (const fx4*)W + (size_t)split * KC * (MSZ / 4) + c4;

    // Issue all KC=32 weight loads back-to-back: ~32 dwordx4 in flight/wave.
    fx4 w[KC];
    #pragma unroll
    for (int ii = 0; ii < KC; ++ii)
        w[ii] = Wp[(size_t)ii * (MSZ / 4)];

    // x slice is wave-uniform (blockIdx-derived index) -> scalar loads,
    // issued while the vector loads are in flight.
    float xr[KC];
    #pragma unroll
    for (int i = 0; i < KC; ++i) xr[i] = x[split * KC + i];

    fx4 acc0 = {0.f, 0.f, 0.f, 0.f};
    fx4 acc1 = {0.f, 0.f, 0.f, 0.f};
    #pragma unroll
    for (int ii = 0; ii < KC; ii += 2) {
        acc0 += xr[ii]     * w[ii];
        acc1 += xr[ii + 1] * w[ii + 1];
    }
    ((fx4*)z_part)[((size_t)split * 3 + gate) * (MSZ / 4) + c4] = acc0 + acc1;
}

// ---------------------------------------------------------------------------
// Kernel B: reduce NSPLIT partials per (gate, col), add bias, LSTM activations.
// h_t[j] = sigmoid(z_o) * tanh( sigmoid(z_i) * tanh(z_c) )   (c0 == 0)
// 3 MB of partials (L2/L3-resident). 32 blocks x 128 threads -> 32 CUs pull
// the 3 MB instead of 16; loads are independent scalar dwords (MLP-covered).
// ---------------------------------------------------------------------------
__global__ __launch_bounds__(128) void k_act(
    const float* __restrict__ z_part,
    const float* __restrict__ b_inpgate,
    const float* __restrict__ b_outgate,
    const float* __restrict__ b_inp,
    float* __restrict__ h_t)
{
    const int j = blockIdx.x * 128 + threadIdx.x;  // 0..4095
    float zi0 = b_inpgate[j], zi1 = 0.f;
    float zo0 = b_outgate[j], zo1 = 0.f;
    float zc0 = b_inp[j],     zc1 = 0.f;
    #pragma unroll 8
    for (int s = 0; s < NSPLIT; s += 2) {
        const float* zp0 = z_part + (size_t)(s)     * 3 * MSZ;
        const float* zp1 = z_part + (size_t)(s + 1) * 3 * MSZ;
        zi0 += zp0[0 * MSZ + j];  zi1 += zp1[0 * MSZ + j];
        zo0 += zp0[1 * MSZ + j];  zo1 += zp1[1 * MSZ + j];
        zc0 += zp0[2 * MSZ + j];  zc1 += zp1[2 * MSZ + j];
    }
    const float zi = zi0 + zi1, zo = zo0 + zo1, zc = zc0 + zc1;
    const float ig  = 1.f / (1.f + __expf(-zi));
    const float og  = 1.f / (1.f + __expf(-zo));
    const float ct  = tanhf(zc);
    const float c_t = ig * ct;            // forget_gate * c0 == 0
    h_t[j] = og * tanhf(c_t);
}

// ---------------------------------------------------------------------------
// Kernel C: outer product out[i][j] = w_hid_out[i] * h_t[j]  (4096x4096 fp32).
// 2048 grid-stride blocks, one nontemporal float4 store per iteration;
// h_t (16 KB) is L1/L2-resident, w_hid_out row value is wave-uniform.
// Pure write stream: 64 MiB; stores are fire-and-forget so write BW-bound.
// ---------------------------------------------------------------------------
#define CBLK 2048
__global__ __launch_bounds__(256) void k_outer(
    const float* __restrict__ w_hid_out,
    const float* __restrict__ h_t,
    fx4* __restrict__ out4)
{
    const fx4* h4 = (const fx4*)h_t;
    int i = blockIdx.x * 256 + threadIdx.x;
    #pragma unroll
    for (int it = 0; it < (MSZ * (MSZ / 4)) / (CBLK * 256); ++it, i += CBLK * 256) {
        const int row = i >> 10;            // / (4096/4)
        const float w = w_hid_out[row];
        const fx4 o = w * h4[i & 1023];
        __builtin_nontemporal_store(o, &out4[i]);
    }
}

extern "C" void kernel_launch(void* const* d_in, const int* in_sizes, int n_in,
                              void* d_out, int out_size, void* d_ws, size_t ws_size,
                              hipStream_t stream) {
    const float* x          = (const float*)d_in[0];
    // h0 = d_in[1], c0 = d_in[2]: zeros, unused (is_reset==1)
    const float* w_inpgate  = (const float*)d_in[3];
    const float* w_inp      = (const float*)d_in[6];
    const float* w_outgate  = (const float*)d_in[11];
    const float* w_hid_out  = (const float*)d_in[14];
    const float* b_inpgate  = (const float*)d_in[15];
    const float* b_inp      = (const float*)d_in[16];
    const float* b_outgate  = (const float*)d_in[18];

    float* z_part = (float*)d_ws;                       // 64 * 3 * 4096 floats = 3 MiB
    float* h_t    = z_part + (size_t)NSPLIT * 3 * MSZ;  // 4096 floats

    k_matvec<<<3 * 4 * NSPLIT, 256, 0, stream>>>(x, w_inpgate, w_outgate, w_inp, z_part);
    k_act<<<MSZ / 128, 128, 0, stream>>>(z_part, b_inpgate, b_outgate, b_inp, h_t);
    k_outer<<<CBLK, 256, 0, stream>>>(w_hid_out, h_t, (fx4*)d_out);
}